// Round 1
// baseline (1539.245 us; speedup 1.0000x reference)
//
#include <hip/hip_runtime.h>
#include <hip/hip_bf16.h>

// GCN forward on MI355X.
//   S1t  = (feat @ W1)^T          bf16 [HID][N]     (computed swapped: A=W1t, Bt=featb)
//   x1   = relu(adj @ S1 + b1)    fp32 -> d_out, bf16 copy x1b [N][HID]
//   S2t  = (x1 @ W2)^T            bf16 [CLS][N]     (swapped: A=W2t, Bt=x1b)
//   x2   = adj @ S2 + b2          split-K partials, fused log_softmax -> d_out+N*HID

#define NROW 10000
#define FIN  512
#define HID  256
#define NCLS 64
#define KSPLIT 4
#define KSPAN  2560   // multiple of 64; last split covers 2320

typedef __bf16 bf8_t __attribute__((ext_vector_type(8)));
typedef __bf16 bf4_t __attribute__((ext_vector_type(4)));
typedef float  f4_t  __attribute__((ext_vector_type(4)));
typedef short  s8_t  __attribute__((ext_vector_type(8)));

// ---------------- converts ----------------
__global__ void cvt_f32_bf16(const float* __restrict__ in, __bf16* __restrict__ out, int n) {
    int stride = gridDim.x * blockDim.x * 4;
    for (int i = (blockIdx.x * blockDim.x + threadIdx.x) * 4; i < n; i += stride) {
        f4_t v = *(const f4_t*)(in + i);
        bf4_t o;
        o[0] = (__bf16)v[0]; o[1] = (__bf16)v[1]; o[2] = (__bf16)v[2]; o[3] = (__bf16)v[3];
        *(bf4_t*)(out + i) = o;
    }
}

// in [K][Nn] fp32 row-major -> out [Nn][K] bf16 (weights only; tiny)
__global__ void cvt_transpose(const float* __restrict__ in, __bf16* __restrict__ out, int K, int Nn) {
    int idx = blockIdx.x * 256 + threadIdx.x;
    if (idx < K * Nn) {
        int k = idx / Nn, n = idx % Nn;
        out[n * K + k] = (__bf16)in[idx];
    }
}

// ---------------- GEMM: D[M][Nn] = A[M][K] * Bt[Nn][K]^T ----------------
// A: fp32 (AF32, converted during staging) or bf16, row-major, leading dim lda.
// Bt: bf16 row-major [Nn][ldb] (K contiguous).
// EPI 0: store bf16 row-major to outB (ldo)
// EPI 1: y=relu(acc+bias[col]); fp32->outF, bf16->outB (both row-major, ldo)
// EPI 2: fp32 partial -> outF + blockIdx.z*partStride
template<int BM, int BN, int BK, bool AF32, int EPI>
__global__ void __launch_bounds__(256, 2)
gemm_bt(const void* __restrict__ Ap, const __bf16* __restrict__ Bt,
        int M, int Nn, int K, int lda, int ldb, int kspan,
        float* __restrict__ outF, __bf16* __restrict__ outB,
        const float* __restrict__ bias, int ldo, long partStride)
{
    constexpr int WM = BM / 2, WN = BN / 2;      // 2x2 waves per block
    constexpr int MI = WM / 16, NI = WN / 16;
    constexpr int LDS_K = BK + 8;                // +16B pad: breaks bank aliasing, keeps 16B align
    __shared__ __bf16 As[BM * LDS_K];
    __shared__ __bf16 Bs[BN * LDS_K];

    const int tid  = threadIdx.x;
    const int lane = tid & 63;
    const int wave = tid >> 6;
    const int wm = wave >> 1, wn = wave & 1;
    const int m0 = blockIdx.x * BM;
    const int n0 = blockIdx.y * BN;
    const int kbase = blockIdx.z * kspan;
    const int kend  = min(K, kbase + kspan);     // always multiple of 8 here

    f4_t acc[MI][NI];
    #pragma unroll
    for (int i = 0; i < MI; i++)
        #pragma unroll
        for (int j = 0; j < NI; j++)
            acc[i][j] = f4_t{0.f, 0.f, 0.f, 0.f};

    const int lrow  = lane & 15;
    const int koff0 = (lane >> 4) * 8;

    for (int k0 = kbase; k0 < kend; k0 += BK) {
        // ---- stage A tile (BM x BK) ----
        if constexpr (AF32) {
            const float* A = (const float*)Ap;
            #pragma unroll
            for (int i = 0; i < BM * BK / 4 / 256; ++i) {
                int idx = tid + i * 256;
                int r = idx / (BK / 4), c = idx % (BK / 4);
                int gm = m0 + r, gk = k0 + c * 4;
                f4_t v = f4_t{0.f, 0.f, 0.f, 0.f};
                if (gm < M && gk < kend) v = *(const f4_t*)(A + (long)gm * lda + gk);
                bf4_t o;
                o[0] = (__bf16)v[0]; o[1] = (__bf16)v[1]; o[2] = (__bf16)v[2]; o[3] = (__bf16)v[3];
                *(bf4_t*)&As[r * LDS_K + c * 4] = o;
            }
        } else {
            const short* A = (const short*)Ap;
            #pragma unroll
            for (int i = 0; i < BM * BK / 8 / 256; ++i) {
                int idx = tid + i * 256;
                int r = idx / (BK / 8), c = idx % (BK / 8);
                int gm = m0 + r, gk = k0 + c * 8;
                s8_t v = s8_t{0,0,0,0,0,0,0,0};
                if (gm < M && gk < kend) v = *(const s8_t*)(A + (long)gm * lda + gk);
                *(s8_t*)&As[r * LDS_K + c * 8] = v;
            }
        }
        // ---- stage B tile (BN x BK) ----
        {
            const short* B = (const short*)Bt;
            #pragma unroll
            for (int i = 0; i < BN * BK / 8 / 256; ++i) {
                int idx = tid + i * 256;
                int r = idx / (BK / 8), c = idx % (BK / 8);
                int gn = n0 + r, gk = k0 + c * 8;
                s8_t v = s8_t{0,0,0,0,0,0,0,0};
                if (gn < Nn && gk < kend) v = *(const s8_t*)(B + (long)gn * ldb + gk);
                *(s8_t*)&Bs[r * LDS_K + c * 8] = v;
            }
        }
        __syncthreads();
        // ---- MFMA over BK (two k-steps of 32) ----
        #pragma unroll
        for (int ks = 0; ks < BK; ks += 32) {
            bf8_t af[MI], bfv[NI];
            #pragma unroll
            for (int mi = 0; mi < MI; mi++)
                af[mi] = *(const bf8_t*)&As[(wm * WM + mi * 16 + lrow) * LDS_K + ks + koff0];
            #pragma unroll
            for (int ni = 0; ni < NI; ni++)
                bfv[ni] = *(const bf8_t*)&Bs[(wn * WN + ni * 16 + lrow) * LDS_K + ks + koff0];
            #pragma unroll
            for (int mi = 0; mi < MI; mi++)
                #pragma unroll
                for (int ni = 0; ni < NI; ni++)
                    acc[mi][ni] = __builtin_amdgcn_mfma_f32_16x16x32_bf16(
                        af[mi], bfv[ni], acc[mi][ni], 0, 0, 0);
        }
        __syncthreads();
    }

    // ---- epilogue ----  C/D layout: col = lane&15, row = (lane>>4)*4 + reg
    const int erow = wm * WM + (lane >> 4) * 4;
    const int ecol = wn * WN + lrow;
    #pragma unroll
    for (int mi = 0; mi < MI; mi++) {
        #pragma unroll
        for (int ni = 0; ni < NI; ni++) {
            #pragma unroll
            for (int r = 0; r < 4; r++) {
                int grow = m0 + erow + mi * 16 + r;
                int gcol = n0 + ecol + ni * 16;
                if (grow < M && gcol < Nn) {
                    float v = acc[mi][ni][r];
                    if constexpr (EPI == 0) {
                        outB[(long)grow * ldo + gcol] = (__bf16)v;
                    } else if constexpr (EPI == 1) {
                        float y = fmaxf(v + bias[gcol], 0.f);
                        outF[(long)grow * ldo + gcol] = y;
                        outB[(long)grow * ldo + gcol] = (__bf16)y;
                    } else {
                        outF[blockIdx.z * partStride + (long)grow * ldo + gcol] = v;
                    }
                }
            }
        }
    }
}

// ---------------- split-K reduce + bias + log_softmax ----------------
// part: [KSPLIT][M][64] fp32. One wave per row; lane = class.
__global__ void logsoftmax_fin(const float* __restrict__ part, const float* __restrict__ b2,
                               float* __restrict__ out, int M) {
    int row  = blockIdx.x * 4 + (threadIdx.x >> 6);
    int lane = threadIdx.x & 63;
    if (row >= M) return;
    float v = b2[lane];
    #pragma unroll
    for (int s = 0; s < KSPLIT; s++) v += part[((long)s * M + row) * NCLS + lane];
    float m = v;
    #pragma unroll
    for (int off = 32; off > 0; off >>= 1) m = fmaxf(m, __shfl_xor(m, off));
    float e = __expf(v - m);
    float sum = e;
    #pragma unroll
    for (int off = 32; off > 0; off >>= 1) sum += __shfl_xor(sum, off);
    out[(long)row * NCLS + lane] = (v - m) - __logf(sum);
}

extern "C" void kernel_launch(void* const* d_in, const int* in_sizes, int n_in,
                              void* d_out, int out_size, void* d_ws, size_t ws_size,
                              hipStream_t stream) {
    const float* feat = (const float*)d_in[0];
    const float* adj  = (const float*)d_in[1];
    const float* W1   = (const float*)d_in[2];
    const float* b1   = (const float*)d_in[3];
    const float* W2   = (const float*)d_in[4];
    const float* b2   = (const float*)d_in[5];
    float* out = (float*)d_out;
    char* ws = (char*)d_ws;

    // workspace layout (all offsets multiple of 256 B) -- ~32.3 MB total
    __bf16* featb = (__bf16*)(ws);                         // [N][FIN]      10,240,000
    __bf16* W1t   = (__bf16*)(ws + 10240000);              // [HID][FIN]       262,144
    __bf16* W2t   = (__bf16*)(ws + 10502144);              // [CLS][HID]        32,768
    __bf16* S1t   = (__bf16*)(ws + 10534912);              // [HID][N]       5,120,000
    __bf16* x1b   = (__bf16*)(ws + 15654912);              // [N][HID]       5,120,000
    __bf16* S2t   = (__bf16*)(ws + 20774912);              // [CLS][N]       1,280,000
    float*  part  = (float*) (ws + 22054912);              // [4][N][CLS]   10,240,000

    cvt_f32_bf16<<<640, 256, 0, stream>>>(feat, featb, NROW * FIN);
    cvt_transpose<<<(FIN * HID + 255) / 256, 256, 0, stream>>>(W1, W1t, FIN, HID);
    cvt_transpose<<<(HID * NCLS + 255) / 256, 256, 0, stream>>>(W2, W2t, HID, NCLS);

    // S1t[HID][N] = W1t @ featb^T   (M=HID=256, Nn=N, K=FIN)
    gemm_bt<128, 128, 64, false, 0><<<dim3(2, 79, 1), 256, 0, stream>>>(
        W1t, featb, HID, NROW, FIN, FIN, FIN, FIN,
        nullptr, S1t, nullptr, NROW, 0);

    // x1 = relu(adj @ S1 + b1)   (M=N, Nn=HID, K=N)
    gemm_bt<128, 128, 64, true, 1><<<dim3(79, 2, 1), 256, 0, stream>>>(
        adj, S1t, NROW, HID, NROW, NROW, NROW, NROW,
        out, x1b, b1, HID, 0);

    // S2t[CLS][N] = W2t @ x1b^T  (M=CLS=64, Nn=N, K=HID)
    gemm_bt<64, 128, 64, false, 0><<<dim3(1, 79, 1), 256, 0, stream>>>(
        W2t, x1b, NCLS, NROW, HID, HID, HID, HID,
        nullptr, S2t, nullptr, NROW, 0);

    // x2 partials = adj @ S2   (M=N, Nn=CLS, K=N, split-K=4)
    gemm_bt<128, 64, 64, true, 2><<<dim3(79, 1, KSPLIT), 256, 0, stream>>>(
        adj, S2t, NROW, NCLS, NROW, NROW, NROW, KSPAN,
        part, nullptr, nullptr, NCLS, (long)NROW * NCLS);

    // reduce + b2 + log_softmax -> second output
    logsoftmax_fin<<<2500, 256, 0, stream>>>(part, b2, out + (long)NROW * HID, NROW);
}

// Round 2
// 886.257 us; speedup vs baseline: 1.7368x; 1.7368x over previous
//
#include <hip/hip_runtime.h>
#include <hip/hip_bf16.h>

// GCN forward on MI355X.
//   S1t  = (feat @ W1)^T          bf16 [HID][N]     (computed swapped: A=W1t, Bt=featb)
//   x1   = relu(adj @ S1 + b1)    split-K=4 partials -> relu_bias_fin -> d_out fp32 + x1b bf16
//   S2t  = (x1 @ W2)^T            bf16 [CLS][N]     (swapped: A=W2t, Bt=x1b)
//   x2   = adj @ S2 + b2          split-K=8 partials, fused log_softmax -> d_out+N*HID

#define NROW 10000
#define FIN  512
#define HID  256
#define NCLS 64
#define KSPLIT2 4
#define KSPAN2  2560   // 4 x 2560 covers 10000 (last span 2320)
#define KSPLIT4 8
#define KSPAN4  1280   // 8 x 1280 covers 10000 (last span 1040)

typedef __bf16 bf8_t __attribute__((ext_vector_type(8)));
typedef __bf16 bf4_t __attribute__((ext_vector_type(4)));
typedef float  f4_t  __attribute__((ext_vector_type(4)));
typedef short  s8_t  __attribute__((ext_vector_type(8)));

// ---------------- converts ----------------
__global__ void cvt_f32_bf16(const float* __restrict__ in, __bf16* __restrict__ out, int n) {
    int stride = gridDim.x * blockDim.x * 4;
    for (int i = (blockIdx.x * blockDim.x + threadIdx.x) * 4; i < n; i += stride) {
        f4_t v = *(const f4_t*)(in + i);
        bf4_t o;
        o[0] = (__bf16)v[0]; o[1] = (__bf16)v[1]; o[2] = (__bf16)v[2]; o[3] = (__bf16)v[3];
        *(bf4_t*)(out + i) = o;
    }
}

// in [K][Nn] fp32 row-major -> out [Nn][K] bf16 (weights only; tiny)
__global__ void cvt_transpose(const float* __restrict__ in, __bf16* __restrict__ out, int K, int Nn) {
    int idx = blockIdx.x * 256 + threadIdx.x;
    if (idx < K * Nn) {
        int k = idx / Nn, n = idx % Nn;
        out[n * K + k] = (__bf16)in[idx];
    }
}

// ---------------- GEMM: D[M][Nn] = A[M][K] * Bt[Nn][K]^T ----------------
// A: fp32 (AF32, converted during staging) or bf16, row-major, leading dim lda.
// Bt: bf16 row-major [Nn][ldb] (K contiguous).
// EPI 0: store bf16 row-major to outB (ldo)
// EPI 2: fp32 partial -> outF + blockIdx.z*partStride
template<int BM, int BN, int BK, bool AF32, int EPI>
__global__ void __launch_bounds__(256, 4)
gemm_bt(const void* __restrict__ Ap, const __bf16* __restrict__ Bt,
        int M, int Nn, int K, int lda, int ldb, int kspan,
        float* __restrict__ outF, __bf16* __restrict__ outB,
        int ldo, long partStride)
{
    constexpr int WM = BM / 2, WN = BN / 2;      // 2x2 waves per block
    constexpr int MI = WM / 16, NI = WN / 16;
    constexpr int LDS_K = BK + 8;                // +16B pad: breaks bank aliasing, keeps 16B align
    __shared__ __bf16 As[BM * LDS_K];
    __shared__ __bf16 Bs[BN * LDS_K];

    const int tid  = threadIdx.x;
    const int lane = tid & 63;
    const int wave = tid >> 6;
    const int wm = wave >> 1, wn = wave & 1;
    const int m0 = blockIdx.x * BM;
    const int n0 = blockIdx.y * BN;
    const int kbase = blockIdx.z * kspan;
    const int kend  = min(K, kbase + kspan);

    f4_t acc[MI][NI];
    #pragma unroll
    for (int i = 0; i < MI; i++)
        #pragma unroll
        for (int j = 0; j < NI; j++)
            acc[i][j] = f4_t{0.f, 0.f, 0.f, 0.f};

    const int lrow  = lane & 15;
    const int koff0 = (lane >> 4) * 8;

    for (int k0 = kbase; k0 < kend; k0 += BK) {
        // ---- stage A tile (BM x BK) ----
        if constexpr (AF32) {
            const float* A = (const float*)Ap;
            #pragma unroll
            for (int i = 0; i < BM * BK / 4 / 256; ++i) {
                int idx = tid + i * 256;
                int r = idx / (BK / 4), c = idx % (BK / 4);
                int gm = m0 + r, gk = k0 + c * 4;
                f4_t v = f4_t{0.f, 0.f, 0.f, 0.f};
                if (gm < M && gk < kend) v = *(const f4_t*)(A + (long)gm * lda + gk);
                bf4_t o;
                o[0] = (__bf16)v[0]; o[1] = (__bf16)v[1]; o[2] = (__bf16)v[2]; o[3] = (__bf16)v[3];
                *(bf4_t*)&As[r * LDS_K + c * 4] = o;
            }
        } else {
            const short* A = (const short*)Ap;
            #pragma unroll
            for (int i = 0; i < BM * BK / 8 / 256; ++i) {
                int idx = tid + i * 256;
                int r = idx / (BK / 8), c = idx % (BK / 8);
                int gm = m0 + r, gk = k0 + c * 8;
                s8_t v = s8_t{0,0,0,0,0,0,0,0};
                if (gm < M && gk < kend) v = *(const s8_t*)(A + (long)gm * lda + gk);
                *(s8_t*)&As[r * LDS_K + c * 8] = v;
            }
        }
        // ---- stage B tile (BN x BK) ----
        {
            const short* B = (const short*)Bt;
            #pragma unroll
            for (int i = 0; i < BN * BK / 8 / 256; ++i) {
                int idx = tid + i * 256;
                int r = idx / (BK / 8), c = idx % (BK / 8);
                int gn = n0 + r, gk = k0 + c * 8;
                s8_t v = s8_t{0,0,0,0,0,0,0,0};
                if (gn < Nn && gk < kend) v = *(const s8_t*)(B + (long)gn * ldb + gk);
                *(s8_t*)&Bs[r * LDS_K + c * 8] = v;
            }
        }
        __syncthreads();
        // ---- MFMA over BK (two k-steps of 32) ----
        #pragma unroll
        for (int ks = 0; ks < BK; ks += 32) {
            bf8_t af[MI], bfv[NI];
            #pragma unroll
            for (int mi = 0; mi < MI; mi++)
                af[mi] = *(const bf8_t*)&As[(wm * WM + mi * 16 + lrow) * LDS_K + ks + koff0];
            #pragma unroll
            for (int ni = 0; ni < NI; ni++)
                bfv[ni] = *(const bf8_t*)&Bs[(wn * WN + ni * 16 + lrow) * LDS_K + ks + koff0];
            #pragma unroll
            for (int mi = 0; mi < MI; mi++)
                #pragma unroll
                for (int ni = 0; ni < NI; ni++)
                    acc[mi][ni] = __builtin_amdgcn_mfma_f32_16x16x32_bf16(
                        af[mi], bfv[ni], acc[mi][ni], 0, 0, 0);
        }
        __syncthreads();
    }

    // ---- epilogue ----  C/D layout: col = lane&15, row = (lane>>4)*4 + reg
    const int erow = wm * WM + (lane >> 4) * 4;
    const int ecol = wn * WN + lrow;
    #pragma unroll
    for (int mi = 0; mi < MI; mi++) {
        #pragma unroll
        for (int ni = 0; ni < NI; ni++) {
            #pragma unroll
            for (int r = 0; r < 4; r++) {
                int grow = m0 + erow + mi * 16 + r;
                int gcol = n0 + ecol + ni * 16;
                if (grow < M && gcol < Nn) {
                    float v = acc[mi][ni][r];
                    if constexpr (EPI == 0) {
                        outB[(long)grow * ldo + gcol] = (__bf16)v;
                    } else {
                        outF[blockIdx.z * partStride + (long)grow * ldo + gcol] = v;
                    }
                }
            }
        }
    }
}

// ---------------- GEMM2 reduce: x1 = relu(sum(part) + b1) ----------------
// part: [KSPLIT2][NROW][HID] fp32. Exactly NROW*HID/4 threads of work.
__global__ void relu_bias_fin(const float* __restrict__ part, const float* __restrict__ b1,
                              float* __restrict__ outF, __bf16* __restrict__ outB) {
    long i = (long)(blockIdx.x * 256 + threadIdx.x) * 4;
    f4_t v = *(const f4_t*)(part + i);
    #pragma unroll
    for (int s = 1; s < KSPLIT2; s++) {
        f4_t p = *(const f4_t*)(part + (long)s * NROW * HID + i);
        v[0] += p[0]; v[1] += p[1]; v[2] += p[2]; v[3] += p[3];
    }
    int col = (int)(i & (HID - 1));
    f4_t b = *(const f4_t*)(b1 + col);
    f4_t y;
    bf4_t yb;
    #pragma unroll
    for (int j = 0; j < 4; j++) {
        y[j] = fmaxf(v[j] + b[j], 0.f);
        yb[j] = (__bf16)y[j];
    }
    *(f4_t*)(outF + i) = y;
    *(bf4_t*)(outB + i) = yb;
}

// ---------------- split-K reduce + bias + log_softmax ----------------
// part: [KSPLIT4][M][64] fp32. One wave per row; lane = class.
__global__ void logsoftmax_fin(const float* __restrict__ part, const float* __restrict__ b2,
                               float* __restrict__ out, int M) {
    int row  = blockIdx.x * 4 + (threadIdx.x >> 6);
    int lane = threadIdx.x & 63;
    if (row >= M) return;
    float v = b2[lane];
    #pragma unroll
    for (int s = 0; s < KSPLIT4; s++) v += part[((long)s * M + row) * NCLS + lane];
    float m = v;
    #pragma unroll
    for (int off = 32; off > 0; off >>= 1) m = fmaxf(m, __shfl_xor(m, off));
    float e = __expf(v - m);
    float sum = e;
    #pragma unroll
    for (int off = 32; off > 0; off >>= 1) sum += __shfl_xor(sum, off);
    out[(long)row * NCLS + lane] = (v - m) - __logf(sum);
}

extern "C" void kernel_launch(void* const* d_in, const int* in_sizes, int n_in,
                              void* d_out, int out_size, void* d_ws, size_t ws_size,
                              hipStream_t stream) {
    const float* feat = (const float*)d_in[0];
    const float* adj  = (const float*)d_in[1];
    const float* W1   = (const float*)d_in[2];
    const float* b1   = (const float*)d_in[3];
    const float* W2   = (const float*)d_in[4];
    const float* b2   = (const float*)d_in[5];
    float* out = (float*)d_out;
    char* ws = (char*)d_ws;

    // workspace layout (offsets multiple of 256 B) -- 63.0 MB total
    __bf16* featb = (__bf16*)(ws);                         // [N][FIN]      10,240,000
    __bf16* W1t   = (__bf16*)(ws + 10240000);              // [HID][FIN]       262,144
    __bf16* W2t   = (__bf16*)(ws + 10502144);              // [CLS][HID]        32,768
    __bf16* S1t   = (__bf16*)(ws + 10534912);              // [HID][N]       5,120,000
    __bf16* x1b   = (__bf16*)(ws + 15654912);              // [N][HID]       5,120,000
    __bf16* S2t   = (__bf16*)(ws + 20774912);              // [CLS][N]       1,280,000
    // partials region (aliased): GEMM2 uses [4][N][HID] f32 = 40,960,000;
    // GEMM4 later reuses the same region as [8][N][CLS] f32 = 20,480,000.
    float*  part  = (float*) (ws + 22054912);

    cvt_f32_bf16<<<640, 256, 0, stream>>>(feat, featb, NROW * FIN);
    cvt_transpose<<<(FIN * HID + 255) / 256, 256, 0, stream>>>(W1, W1t, FIN, HID);
    cvt_transpose<<<(HID * NCLS + 255) / 256, 256, 0, stream>>>(W2, W2t, HID, NCLS);

    // S1t[HID][N] = W1t @ featb^T   (M=HID=256, Nn=N, K=FIN)
    gemm_bt<64, 128, 64, false, 0><<<dim3(4, 79, 1), 256, 0, stream>>>(
        W1t, featb, HID, NROW, FIN, FIN, FIN, FIN,
        nullptr, S1t, NROW, 0);

    // x1 partials = adj @ S1   (M=N, Nn=HID, K=N, split-K=4)
    gemm_bt<64, 128, 64, true, 2><<<dim3(157, 2, KSPLIT2), 256, 0, stream>>>(
        adj, S1t, NROW, HID, NROW, NROW, NROW, KSPAN2,
        part, nullptr, HID, (long)NROW * HID);

    // x1 = relu(sum + b1) -> out fp32, x1b bf16
    relu_bias_fin<<<NROW * HID / 4 / 256, 256, 0, stream>>>(part, b1, out, x1b);

    // S2t[CLS][N] = W2t @ x1b^T  (M=CLS=64, Nn=N, K=HID)
    gemm_bt<64, 64, 64, false, 0><<<dim3(1, 157, 1), 256, 0, stream>>>(
        W2t, x1b, NCLS, NROW, HID, HID, HID, HID,
        nullptr, S2t, NROW, 0);

    // x2 partials = adj @ S2   (M=N, Nn=CLS, K=N, split-K=8)
    gemm_bt<64, 64, 64, true, 2><<<dim3(157, 1, KSPLIT4), 256, 0, stream>>>(
        adj, S2t, NROW, NCLS, NROW, NROW, NROW, KSPAN4,
        part, nullptr, NCLS, (long)NROW * NCLS);

    // reduce + b2 + log_softmax -> second output
    logsoftmax_fin<<<2500, 256, 0, stream>>>(part, b2, out + (long)NROW * HID, NROW);
}

// Round 3
// 751.936 us; speedup vs baseline: 2.0470x; 1.1786x over previous
//
#include <hip/hip_runtime.h>
#include <hip/hip_bf16.h>

// GCN forward on MI355X.
//   S1t  = (feat @ W1)^T          bf16 [HID][N]     (computed swapped: A=W1t, Bt=featb)
//   x1   = relu(adj @ S1 + b1)    split-K=4 partials -> relu_bias_fin -> d_out fp32 + x1b bf16
//   S2t  = (x1 @ W2)^T            bf16 [CLS][N]     (swapped: A=W2t, Bt=x1b)
//   x2   = adj @ S2 + b2          split-K=8 partials, fused log_softmax -> d_out+N*HID
//
// R3: register-prefetch software pipeline in gemm_bt. Round-2 counters showed
// MfmaUtil 6% / VALU 7% / HBM 17% / occ 31% -- pure latency-bound burst-wait:
// every iter all waves issued loads then sat in vmcnt(0) before ds_write.
// Now tile k+1's global loads are issued before tile k's MFMA phase, so the
// vmcnt wait lands after a full iteration of compute+barrier overlap.

#define NROW 10000
#define FIN  512
#define HID  256
#define NCLS 64
#define KSPLIT2 4
#define KSPAN2  2560   // 4 x 2560 covers 10000 (last span 2320)
#define KSPLIT4 8
#define KSPAN4  1280   // 8 x 1280 covers 10000 (last span 1040)

typedef __bf16 bf8_t __attribute__((ext_vector_type(8)));
typedef __bf16 bf4_t __attribute__((ext_vector_type(4)));
typedef float  f4_t  __attribute__((ext_vector_type(4)));
typedef short  s8_t  __attribute__((ext_vector_type(8)));

// ---------------- converts ----------------
__global__ void cvt_f32_bf16(const float* __restrict__ in, __bf16* __restrict__ out, int n) {
    int stride = gridDim.x * blockDim.x * 4;
    for (int i = (blockIdx.x * blockDim.x + threadIdx.x) * 4; i < n; i += stride) {
        f4_t v = *(const f4_t*)(in + i);
        bf4_t o;
        o[0] = (__bf16)v[0]; o[1] = (__bf16)v[1]; o[2] = (__bf16)v[2]; o[3] = (__bf16)v[3];
        *(bf4_t*)(out + i) = o;
    }
}

// in [K][Nn] fp32 row-major -> out [Nn][K] bf16 (weights only; tiny)
__global__ void cvt_transpose(const float* __restrict__ in, __bf16* __restrict__ out, int K, int Nn) {
    int idx = blockIdx.x * 256 + threadIdx.x;
    if (idx < K * Nn) {
        int k = idx / Nn, n = idx % Nn;
        out[n * K + k] = (__bf16)in[idx];
    }
}

// ---------------- GEMM: D[M][Nn] = A[M][K] * Bt[Nn][K]^T ----------------
// A: fp32 (AF32, converted during staging) or bf16, row-major, leading dim lda.
// Bt: bf16 row-major [Nn][ldb] (K contiguous).
// EPI 0: store bf16 row-major to outB (ldo)
// EPI 2: fp32 partial -> outF + blockIdx.z*partStride
template<int BM, int BN, int BK, bool AF32, int EPI>
__global__ void __launch_bounds__(256, 4)
gemm_bt(const void* __restrict__ Ap, const __bf16* __restrict__ Bt,
        int M, int Nn, int K, int lda, int ldb, int kspan,
        float* __restrict__ outF, __bf16* __restrict__ outB,
        int ldo, long partStride)
{
    constexpr int WM = BM / 2, WN = BN / 2;      // 2x2 waves per block
    constexpr int MI = WM / 16, NI = WN / 16;
    constexpr int LDS_K = BK + 8;                // +16B pad: breaks bank aliasing, keeps 16B align
    constexpr int ACH = AF32 ? (BM * BK / 4 / 256) : (BM * BK / 8 / 256);
    constexpr int BCH = BN * BK / 8 / 256;
    __shared__ __bf16 As[BM * LDS_K];
    __shared__ __bf16 Bs[BN * LDS_K];

    const int tid  = threadIdx.x;
    const int lane = tid & 63;
    const int wave = tid >> 6;
    const int wm = wave >> 1, wn = wave & 1;
    const int m0 = blockIdx.x * BM;
    const int n0 = blockIdx.y * BN;
    const int kbase = blockIdx.z * kspan;
    const int kend  = min(K, kbase + kspan);

    f4_t acc[MI][NI];
    #pragma unroll
    for (int i = 0; i < MI; i++)
        #pragma unroll
        for (int j = 0; j < NI; j++)
            acc[i][j] = f4_t{0.f, 0.f, 0.f, 0.f};

    const int lrow  = lane & 15;
    const int koff0 = (lane >> 4) * 8;

    // prefetch registers
    f4_t aPreF[AF32 ? ACH : 1];
    s8_t aPreH[AF32 ? 1 : ACH];
    s8_t bPre[BCH];

    // ---- staging helpers (coords are compile-time-derived from tid) ----
    auto issueA = [&](int k0) {
        if constexpr (AF32) {
            const float* A = (const float*)Ap;
            #pragma unroll
            for (int i = 0; i < ACH; ++i) {
                int idx = tid + i * 256;
                int r = idx / (BK / 4), c = idx % (BK / 4);
                int gm = m0 + r, gk = k0 + c * 4;
                f4_t v = f4_t{0.f, 0.f, 0.f, 0.f};
                if (gm < M && gk < kend) v = *(const f4_t*)(A + (long)gm * lda + gk);
                aPreF[i] = v;
            }
        } else {
            const short* A = (const short*)Ap;
            #pragma unroll
            for (int i = 0; i < ACH; ++i) {
                int idx = tid + i * 256;
                int r = idx / (BK / 8), c = idx % (BK / 8);
                int gm = m0 + r, gk = k0 + c * 8;
                s8_t v = s8_t{0,0,0,0,0,0,0,0};
                if (gm < M && gk < kend) v = *(const s8_t*)(A + (long)gm * lda + gk);
                aPreH[i] = v;
            }
        }
    };
    auto issueB = [&](int k0) {
        const short* B = (const short*)Bt;
        #pragma unroll
        for (int i = 0; i < BCH; ++i) {
            int idx = tid + i * 256;
            int r = idx / (BK / 8), c = idx % (BK / 8);
            int gn = n0 + r, gk = k0 + c * 8;
            s8_t v = s8_t{0,0,0,0,0,0,0,0};
            if (gn < Nn && gk < kend) v = *(const s8_t*)(B + (long)gn * ldb + gk);
            bPre[i] = v;
        }
    };
    auto storeAB = [&]() {
        if constexpr (AF32) {
            #pragma unroll
            for (int i = 0; i < ACH; ++i) {
                int idx = tid + i * 256;
                int r = idx / (BK / 4), c = idx % (BK / 4);
                f4_t v = aPreF[i];
                bf4_t o;
                o[0] = (__bf16)v[0]; o[1] = (__bf16)v[1]; o[2] = (__bf16)v[2]; o[3] = (__bf16)v[3];
                *(bf4_t*)&As[r * LDS_K + c * 4] = o;
            }
        } else {
            #pragma unroll
            for (int i = 0; i < ACH; ++i) {
                int idx = tid + i * 256;
                int r = idx / (BK / 8), c = idx % (BK / 8);
                *(s8_t*)&As[r * LDS_K + c * 8] = aPreH[i];
            }
        }
        #pragma unroll
        for (int i = 0; i < BCH; ++i) {
            int idx = tid + i * 256;
            int r = idx / (BK / 8), c = idx % (BK / 8);
            *(s8_t*)&Bs[r * LDS_K + c * 8] = bPre[i];
        }
    };

    // ---- pipelined main loop: issue(k+1) before compute(k) ----
    issueA(kbase);
    issueB(kbase);
    for (int k0 = kbase; k0 < kend; k0 += BK) {
        storeAB();                 // vmcnt wait happens here, one iter after issue
        __syncthreads();
        int kn = k0 + BK;
        if (kn < kend) { issueA(kn); issueB(kn); }
        #pragma unroll
        for (int ks = 0; ks < BK; ks += 32) {
            bf8_t af[MI], bfv[NI];
            #pragma unroll
            for (int mi = 0; mi < MI; mi++)
                af[mi] = *(const bf8_t*)&As[(wm * WM + mi * 16 + lrow) * LDS_K + ks + koff0];
            #pragma unroll
            for (int ni = 0; ni < NI; ni++)
                bfv[ni] = *(const bf8_t*)&Bs[(wn * WN + ni * 16 + lrow) * LDS_K + ks + koff0];
            #pragma unroll
            for (int mi = 0; mi < MI; mi++)
                #pragma unroll
                for (int ni = 0; ni < NI; ni++)
                    acc[mi][ni] = __builtin_amdgcn_mfma_f32_16x16x32_bf16(
                        af[mi], bfv[ni], acc[mi][ni], 0, 0, 0);
        }
        __syncthreads();
    }

    // ---- epilogue ----  C/D layout: col = lane&15, row = (lane>>4)*4 + reg
    const int erow = wm * WM + (lane >> 4) * 4;
    const int ecol = wn * WN + lrow;
    #pragma unroll
    for (int mi = 0; mi < MI; mi++) {
        #pragma unroll
        for (int ni = 0; ni < NI; ni++) {
            #pragma unroll
            for (int r = 0; r < 4; r++) {
                int grow = m0 + erow + mi * 16 + r;
                int gcol = n0 + ecol + ni * 16;
                if (grow < M && gcol < Nn) {
                    float v = acc[mi][ni][r];
                    if constexpr (EPI == 0) {
                        outB[(long)grow * ldo + gcol] = (__bf16)v;
                    } else {
                        outF[blockIdx.z * partStride + (long)grow * ldo + gcol] = v;
                    }
                }
            }
        }
    }
}

// ---------------- GEMM2 reduce: x1 = relu(sum(part) + b1) ----------------
// part: [KSPLIT2][NROW][HID] fp32. Exactly NROW*HID/4 threads of work.
__global__ void relu_bias_fin(const float* __restrict__ part, const float* __restrict__ b1,
                              float* __restrict__ outF, __bf16* __restrict__ outB) {
    long i = (long)(blockIdx.x * 256 + threadIdx.x) * 4;
    f4_t v = *(const f4_t*)(part + i);
    #pragma unroll
    for (int s = 1; s < KSPLIT2; s++) {
        f4_t p = *(const f4_t*)(part + (long)s * NROW * HID + i);
        v[0] += p[0]; v[1] += p[1]; v[2] += p[2]; v[3] += p[3];
    }
    int col = (int)(i & (HID - 1));
    f4_t b = *(const f4_t*)(b1 + col);
    f4_t y;
    bf4_t yb;
    #pragma unroll
    for (int j = 0; j < 4; j++) {
        y[j] = fmaxf(v[j] + b[j], 0.f);
        yb[j] = (__bf16)y[j];
    }
    *(f4_t*)(outF + i) = y;
    *(bf4_t*)(outB + i) = yb;
}

// ---------------- split-K reduce + bias + log_softmax ----------------
// part: [KSPLIT4][M][64] fp32. One wave per row; lane = class.
__global__ void logsoftmax_fin(const float* __restrict__ part, const float* __restrict__ b2,
                               float* __restrict__ out, int M) {
    int row  = blockIdx.x * 4 + (threadIdx.x >> 6);
    int lane = threadIdx.x & 63;
    if (row >= M) return;
    float v = b2[lane];
    #pragma unroll
    for (int s = 0; s < KSPLIT4; s++) v += part[((long)s * M + row) * NCLS + lane];
    float m = v;
    #pragma unroll
    for (int off = 32; off > 0; off >>= 1) m = fmaxf(m, __shfl_xor(m, off));
    float e = __expf(v - m);
    float sum = e;
    #pragma unroll
    for (int off = 32; off > 0; off >>= 1) sum += __shfl_xor(sum, off);
    out[(long)row * NCLS + lane] = (v - m) - __logf(sum);
}

extern "C" void kernel_launch(void* const* d_in, const int* in_sizes, int n_in,
                              void* d_out, int out_size, void* d_ws, size_t ws_size,
                              hipStream_t stream) {
    const float* feat = (const float*)d_in[0];
    const float* adj  = (const float*)d_in[1];
    const float* W1   = (const float*)d_in[2];
    const float* b1   = (const float*)d_in[3];
    const float* W2   = (const float*)d_in[4];
    const float* b2   = (const float*)d_in[5];
    float* out = (float*)d_out;
    char* ws = (char*)d_ws;

    // workspace layout (offsets multiple of 256 B) -- 63.0 MB total
    __bf16* featb = (__bf16*)(ws);                         // [N][FIN]      10,240,000
    __bf16* W1t   = (__bf16*)(ws + 10240000);              // [HID][FIN]       262,144
    __bf16* W2t   = (__bf16*)(ws + 10502144);              // [CLS][HID]        32,768
    __bf16* S1t   = (__bf16*)(ws + 10534912);              // [HID][N]       5,120,000
    __bf16* x1b   = (__bf16*)(ws + 15654912);              // [N][HID]       5,120,000
    __bf16* S2t   = (__bf16*)(ws + 20774912);              // [CLS][N]       1,280,000
    // partials region (aliased): GEMM2 uses [4][N][HID] f32 = 40,960,000;
    // GEMM4 later reuses the same region as [8][N][CLS] f32 = 20,480,000.
    float*  part  = (float*) (ws + 22054912);

    cvt_f32_bf16<<<640, 256, 0, stream>>>(feat, featb, NROW * FIN);
    cvt_transpose<<<(FIN * HID + 255) / 256, 256, 0, stream>>>(W1, W1t, FIN, HID);
    cvt_transpose<<<(HID * NCLS + 255) / 256, 256, 0, stream>>>(W2, W2t, HID, NCLS);

    // S1t[HID][N] = W1t @ featb^T   (M=HID=256, Nn=N, K=FIN)
    gemm_bt<64, 128, 64, false, 0><<<dim3(4, 79, 1), 256, 0, stream>>>(
        W1t, featb, HID, NROW, FIN, FIN, FIN, FIN,
        nullptr, S1t, NROW, 0);

    // x1 partials = adj @ S1   (M=N, Nn=HID, K=N, split-K=4)
    gemm_bt<64, 128, 64, true, 2><<<dim3(157, 2, KSPLIT2), 256, 0, stream>>>(
        adj, S1t, NROW, HID, NROW, NROW, NROW, KSPAN2,
        part, nullptr, HID, (long)NROW * HID);

    // x1 = relu(sum + b1) -> out fp32, x1b bf16
    relu_bias_fin<<<NROW * HID / 4 / 256, 256, 0, stream>>>(part, b1, out, x1b);

    // S2t[CLS][N] = W2t @ x1b^T  (M=CLS=64, Nn=N, K=HID)
    gemm_bt<64, 64, 64, false, 0><<<dim3(1, 157, 1), 256, 0, stream>>>(
        W2t, x1b, NCLS, NROW, HID, HID, HID, HID,
        nullptr, S2t, NROW, 0);

    // x2 partials = adj @ S2   (M=N, Nn=CLS, K=N, split-K=8)
    gemm_bt<64, 64, 64, true, 2><<<dim3(157, 1, KSPLIT4), 256, 0, stream>>>(
        adj, S2t, NROW, NCLS, NROW, NROW, NROW, KSPAN4,
        part, nullptr, NCLS, (long)NROW * NCLS);

    // reduce + b2 + log_softmax -> second output
    logsoftmax_fin<<<2500, 256, 0, stream>>>(part, b2, out + (long)NROW * HID, NROW);
}